// Round 3
// baseline (347.846 us; speedup 1.0000x reference)
//
#include <hip/hip_runtime.h>

#define BN 4
#define EN 32
#define NPIX (512 * 512)   // 262144 = 2^18
#define CSEG 2048
#define NEDGE 8192

#define DELTA_VAR 0.1f
#define DELTA_DIST 0.3f

// ======================= sort-based path =======================

// -------- kA: counts histogram via direct global int atomics --------
__global__ __launch_bounds__(256) void rag_hist(
    const int* __restrict__ seg, int* __restrict__ counts) {
  const int i = blockIdx.x * 256 + threadIdx.x;  // over BN*NPIX
  const int b = i >> 18;
  const int s = seg[i];
  atomicAdd(&counts[b * CSEG + s], 1);
}

// -------- kB: per-sample exclusive scan -> base, cursor --------
__global__ __launch_bounds__(1024) void rag_scan(
    const int* __restrict__ counts, int* __restrict__ base,
    int* __restrict__ cursor) {
  __shared__ int sc[2][CSEG];
  const int b = blockIdx.x;
  const int t = threadIdx.x;
  for (int i = t; i < CSEG; i += 1024) sc[0][i] = counts[b * CSEG + i];
  __syncthreads();
  int cur = 0;
  for (int off = 1; off < CSEG; off <<= 1) {
    for (int i = t; i < CSEG; i += 1024) {
      int v = sc[cur][i];
      if (i >= off) v += sc[cur][i - off];
      sc[cur ^ 1][i] = v;
    }
    cur ^= 1;
    __syncthreads();
  }
  for (int i = t; i < CSEG; i += 1024) {
    const int ex = (i == 0) ? 0 : sc[cur][i - 1];
    base[b * CSEG + i] = ex;
    cursor[b * CSEG + i] = ex;
  }
}

// -------- kC: register-transpose + scatter rows to segment-sorted order ----
// thread <-> pixel; 32 coalesced channel loads; 128B row store to pos.
__global__ __launch_bounds__(512) void rag_scatter(
    const float* __restrict__ emb, const int* __restrict__ seg,
    int* __restrict__ cursor, float* __restrict__ sorted, int b0) {
  const int tile = blockIdx.x & 511;      // 512 tiles/sample
  const int bl = blockIdx.x >> 9;         // local sample in group
  const int b = b0 + bl;
  const int p = tile * 512 + threadIdx.x; // 512 px per tile
  const int s = seg[(size_t)b * NPIX + p];
  const int pos = atomicAdd(&cursor[b * CSEG + s], 1);
  const float* __restrict__ eb = emb + (size_t)b * EN * NPIX + p;
  float v[EN];
#pragma unroll
  for (int e = 0; e < EN; e++) v[e] = eb[(size_t)e * NPIX];
  float* __restrict__ dst = sorted + ((size_t)bl * NPIX + pos) * EN;
#pragma unroll
  for (int e = 0; e < EN; e += 4) {
    *(float4*)(dst + e) = make_float4(v[e], v[e + 1], v[e + 2], v[e + 3]);
  }
}

// -------- kD: per-segment reduce + normalize + fused intra --------
#define STASH 256
__global__ __launch_bounds__(256) void rag_reduce_intra(
    const float* __restrict__ sorted, const int* __restrict__ base,
    float* __restrict__ means, float* __restrict__ out, int b0) {
  const int c = blockIdx.x & (CSEG - 1);
  const int bl = blockIdx.x >> 11;
  const int b = b0 + bl;
  const int bs = base[b * CSEG + c];
  const int be = (c == CSEG - 1) ? NPIX : base[b * CSEG + c + 1];
  const int cnt = be - bs;

  __shared__ float stash[STASH * EN];  // 32 KB
  __shared__ float red[8][EN];
  __shared__ float mvec[EN];
  __shared__ float ws4[4];

  const int e = threadIdx.x & 31;
  const int rg = threadIdx.x >> 5;  // 8 row-groups
  const float* __restrict__ src = sorted + ((size_t)bl * NPIX + bs) * EN;

  float acc = 0.0f;
  for (int r = rg; r < cnt; r += 8) {
    const float v = src[(size_t)r * EN + e];
    if (r < STASH) stash[r * EN + e] = v;
    acc += v;
  }
  red[rg][e] = acc;
  __syncthreads();

  if (threadIdx.x < 32) {
    float s = 0.0f;
#pragma unroll
    for (int r = 0; r < 8; r++) s += red[r][threadIdx.x];
    const float inv = 1.0f / fmaxf((float)cnt, 1.0f);
    float m = s * inv;
    float sq = m * m;
#pragma unroll
    for (int o = 16; o > 0; o >>= 1) sq += __shfl_xor(sq, o, 64);
    const float sc = 1.0f / fmaxf(sqrtf(sq), 1e-10f);
    m *= sc;
    mvec[threadIdx.x] = m;
    means[((size_t)b * CSEG + c) * EN + threadIdx.x] = m;
  }
  __syncthreads();

  // intra: dot(mean, row) per stored row
  float ia = 0.0f;
  const float me = mvec[e];
  for (int r = rg; r < cnt; r += 8) {
    const float v = (r < STASH) ? stash[r * EN + e] : src[(size_t)r * EN + e];
    float p = me * v;
#pragma unroll
    for (int o = 16; o > 0; o >>= 1) p += __shfl_xor(p, o, 64);
    if (e == 0) {
      const float d = 1.0f - p - DELTA_VAR;
      if (d > 0.0f) ia += d;
    }
  }
  for (int o = 32; o > 0; o >>= 1) ia += __shfl_down(ia, o, 64);
  if ((threadIdx.x & 63) == 0) ws4[threadIdx.x >> 6] = ia;
  __syncthreads();
  if (threadIdx.x == 0 && cnt > 0) {
    const float s = ws4[0] + ws4[1] + ws4[2] + ws4[3];
    atomicAdd(out, s * (1.0f / CSEG) / (float)cnt);
  }
}

// -------- kE: inter loss over RAG edges --------
#define JTHREADS 256
__global__ __launch_bounds__(JTHREADS) void rag_inter(
    const int* __restrict__ edges, const float* __restrict__ weights,
    const float* __restrict__ means, float* __restrict__ out) {
  const int idx = blockIdx.x * JTHREADS + threadIdx.x;
  float val = 0.0f;
  if (idx < BN * NEDGE) {
    const int b = idx >> 13;
    const int k = idx & (NEDGE - 1);
    const int e0 = edges[(size_t)b * 2 * NEDGE + k];
    const int e1 = edges[(size_t)b * 2 * NEDGE + NEDGE + k];
    const float w = weights[idx];
    const float4* __restrict__ m0 =
        (const float4*)(means + ((size_t)b * CSEG + e0) * EN);
    const float4* __restrict__ m1 =
        (const float4*)(means + ((size_t)b * CSEG + e1) * EN);
    float dot = 0.0f;
#pragma unroll
    for (int e4 = 0; e4 < EN / 4; e4++) {
      const float4 a = m0[e4];
      const float4 c = m1[e4];
      dot += a.x * c.x + a.y * c.y + a.z * c.z + a.w * c.w;
    }
    val = fmaxf(DELTA_DIST - (1.0f - dot) * w, 0.0f);
  }
  for (int o = 32; o > 0; o >>= 1) val += __shfl_down(val, o, 64);
  __shared__ float wsum[JTHREADS / 64];
  const int lane = threadIdx.x & 63;
  const int wid = threadIdx.x >> 6;
  if (lane == 0) wsum[wid] = val;
  __syncthreads();
  if (threadIdx.x == 0) {
    float bsum = 0.0f;
#pragma unroll
    for (int w = 0; w < JTHREADS / 64; w++) bsum += wsum[w];
    atomicAdd(out, bsum * (1.0f / NEDGE));
  }
}

// ======================= tiny-ws fallback (proven round-1/2 path) ==========
#define ATHREADS 512
#define FECHUNK 8
#define FNECH (EN / FECHUNK)
#define FPIXBLK 32
#define FPPB (NPIX / FPIXBLK)
__global__ __launch_bounds__(ATHREADS) void rag_accum_atomic(
    const float* __restrict__ emb, const int* __restrict__ seg,
    float* __restrict__ counts, float* __restrict__ sums) {
  __shared__ float lsum[FECHUNK * CSEG];
  __shared__ float lcnt[CSEG];
  const int blk = blockIdx.x;
  const int pb = blk % FPIXBLK;
  const int ech = (blk / FPIXBLK) % FNECH;
  const int b = blk / (FPIXBLK * FNECH);
  for (int i = threadIdx.x; i < FECHUNK * CSEG; i += ATHREADS) lsum[i] = 0.0f;
  if (ech == 0)
    for (int i = threadIdx.x; i < CSEG; i += ATHREADS) lcnt[i] = 0.0f;
  __syncthreads();
  const int p0 = pb * FPPB;
  const float* __restrict__ eb = emb + ((size_t)b * EN + (size_t)ech * FECHUNK) * NPIX;
  const int* __restrict__ sb = seg + (size_t)b * NPIX;
  for (int p = p0 + threadIdx.x; p < p0 + FPPB; p += ATHREADS) {
    const int s = sb[p];
    if (ech == 0) atomicAdd(&lcnt[s], 1.0f);
#pragma unroll
    for (int e = 0; e < FECHUNK; e++)
      atomicAdd(&lsum[e * CSEG + s], eb[(size_t)e * NPIX + p]);
  }
  __syncthreads();
  float* __restrict__ gs = sums + (size_t)b * EN * CSEG;
  for (int i = threadIdx.x; i < FECHUNK * CSEG; i += ATHREADS) {
    const float v = lsum[i];
    if (v != 0.0f) {
      const int e = i / CSEG;
      const int c = i - e * CSEG;
      atomicAdd(&gs[(size_t)(ech * FECHUNK + e) * CSEG + c], v);
    }
  }
  if (ech == 0) {
    float* __restrict__ gc = counts + (size_t)b * CSEG;
    for (int i = threadIdx.x; i < CSEG; i += ATHREADS) {
      const float v = lcnt[i];
      if (v != 0.0f) atomicAdd(&gc[i], v);
    }
  }
}

__global__ __launch_bounds__(256) void rag_finalize(
    const float* __restrict__ counts, const float* __restrict__ sums,
    float* __restrict__ means) {
  const int idx = blockIdx.x * 256 + threadIdx.x;
  if (idx >= BN * CSEG) return;
  const int b = idx / CSEG;
  const int c = idx - b * CSEG;
  const float inv = 1.0f / fmaxf(counts[idx], 1.0f);
  const float* __restrict__ sbase = sums + (size_t)b * EN * CSEG + c;
  float m[EN];
  float nrm = 0.0f;
#pragma unroll
  for (int e = 0; e < EN; e++) {
    const float v = sbase[(size_t)e * CSEG] * inv;
    m[e] = v;
    nrm += v * v;
  }
  const float s = 1.0f / fmaxf(sqrtf(nrm), 1e-10f);
  float* __restrict__ mb = means + (size_t)idx * EN;
#pragma unroll
  for (int e = 0; e < EN; e++) mb[e] = m[e] * s;
}

#define ITHREADS 256
__global__ __launch_bounds__(ITHREADS) void rag_intra(
    const float* __restrict__ emb, const int* __restrict__ seg,
    const float* __restrict__ counts, const float* __restrict__ means,
    float* __restrict__ out) {
  float acc = 0.0f;
  const int total = BN * NPIX;
  for (int i = blockIdx.x * ITHREADS + threadIdx.x; i < total;
       i += gridDim.x * ITHREADS) {
    const int b = i >> 18;
    const int p = i & (NPIX - 1);
    const int s = seg[i];
    const float4* __restrict__ mv =
        (const float4*)(means + ((size_t)b * CSEG + s) * EN);
    const float* __restrict__ eb = emb + (size_t)b * EN * NPIX + p;
    float dot = 0.0f;
#pragma unroll
    for (int e4 = 0; e4 < EN / 4; e4++) {
      const float4 m4 = mv[e4];
      dot += m4.x * eb[(size_t)(e4 * 4 + 0) * NPIX];
      dot += m4.y * eb[(size_t)(e4 * 4 + 1) * NPIX];
      dot += m4.z * eb[(size_t)(e4 * 4 + 2) * NPIX];
      dot += m4.w * eb[(size_t)(e4 * 4 + 3) * NPIX];
    }
    const float d = 1.0f - dot - DELTA_VAR;
    if (d > 0.0f) acc += d / counts[b * CSEG + s];
  }
  for (int o = 32; o > 0; o >>= 1) acc += __shfl_down(acc, o, 64);
  __shared__ float wsum[ITHREADS / 64];
  const int lane = threadIdx.x & 63;
  const int wid = threadIdx.x >> 6;
  if (lane == 0) wsum[wid] = acc;
  __syncthreads();
  if (threadIdx.x == 0) {
    float bsum = 0.0f;
#pragma unroll
    for (int w = 0; w < ITHREADS / 64; w++) bsum += wsum[w];
    atomicAdd(out, bsum * (1.0f / CSEG));
  }
}

// ======================= launch =======================
extern "C" void kernel_launch(void* const* d_in, const int* in_sizes, int n_in,
                              void* d_out, int out_size, void* d_ws, size_t ws_size,
                              hipStream_t stream) {
  const float* emb = (const float*)d_in[0];     // [B][E][H][W]
  const int* seg = (const int*)d_in[1];         // [B][1][H][W]
  const int* edges = (const int*)d_in[2];       // [B][2][NEDGE]
  const float* weights = (const float*)d_in[3]; // [B][NEDGE]
  float* out = (float*)d_out;

  hipMemsetAsync(d_out, 0, (size_t)out_size * sizeof(float), stream);

  const size_t ws_elems = ws_size / 4;
  // head: counts_i, base_i, cursor_i (int, BN*CSEG each), means (f, BN*CSEG*EN)
  const size_t HEAD = (size_t)3 * BN * CSEG + (size_t)BN * CSEG * EN;

  int g = 0;
  {
    const int cands[3] = {4, 2, 1};
    for (int k = 0; k < 3; k++) {
      if (HEAD + (size_t)cands[k] * NPIX * EN <= ws_elems) { g = cands[k]; break; }
    }
  }

  if (g > 0) {
    int* counts_i = (int*)d_ws;
    int* base_i = counts_i + BN * CSEG;
    int* cursor_i = base_i + BN * CSEG;
    float* means = (float*)(cursor_i + BN * CSEG);
    float* sorted = means + (size_t)BN * CSEG * EN;

    hipMemsetAsync(counts_i, 0, (size_t)BN * CSEG * sizeof(int), stream);
    rag_hist<<<BN * NPIX / 256, 256, 0, stream>>>(seg, counts_i);
    rag_scan<<<BN, 1024, 0, stream>>>(counts_i, base_i, cursor_i);
    for (int b0 = 0; b0 < BN; b0 += g) {
      rag_scatter<<<g * 512, 512, 0, stream>>>(emb, seg, cursor_i, sorted, b0);
      rag_reduce_intra<<<g * CSEG, 256, 0, stream>>>(sorted, base_i, means, out, b0);
    }
    rag_inter<<<(BN * NEDGE + JTHREADS - 1) / JTHREADS, JTHREADS, 0, stream>>>(
        edges, weights, means, out);
  } else {
    // tiny-ws fallback: LDS-atomic path (proven, slow)
    float* counts = (float*)d_ws;
    float* sums = counts + (size_t)BN * CSEG;
    float* means = sums + (size_t)BN * EN * CSEG;
    hipMemsetAsync(d_ws, 0,
                   ((size_t)BN * CSEG + (size_t)BN * EN * CSEG) * sizeof(float),
                   stream);
    rag_accum_atomic<<<BN * FNECH * FPIXBLK, ATHREADS, 0, stream>>>(emb, seg,
                                                                    counts, sums);
    rag_finalize<<<(BN * CSEG + 255) / 256, 256, 0, stream>>>(counts, sums, means);
    rag_intra<<<1024, ITHREADS, 0, stream>>>(emb, seg, counts, means, out);
    rag_inter<<<(BN * NEDGE + JTHREADS - 1) / JTHREADS, JTHREADS, 0, stream>>>(
        edges, weights, means, out);
  }
}